// Round 5
// baseline (808.254 us; speedup 1.0000x reference)
//
#include <hip/hip_runtime.h>
#include <hip/hip_fp16.h>
#include <hip/hip_cooperative_groups.h>

namespace cg = cooperative_groups;

// B=64, I=2048, D=8, O=32, K=16.  e-layout o-major: e = o*16 + k.
// Fused cooperative kernel: 512 blocks x 512 threads = 2 blocks/CU x 256 CU
// (exact co-residency). W regs + x_lds staged ONCE; 3 rounds of
// {pass -> grid.sync -> reduce -> grid.sync} replace 6 dispatches.
// Fallback to the 6-launch path if cooperative launch is rejected.

struct __align__(16) H8 { __half2 a, b, c, d; };
struct __align__(8)  H4 { __half2 a, b; };

template<int CTRL>
__device__ __forceinline__ float dppadd(float v) {   // v + dpp_perm(v), VALU-only
    return v + __int_as_float(__builtin_amdgcn_update_dpp(
        0, __float_as_int(v), CTRL, 0xF, 0xF, true));
}

// ---------------------------------------------------------------------------
__global__ __launch_bounds__(512, 4)   // <=128 VGPR -> 2 blocks/CU guaranteed
void fused_kernel(const float* __restrict__ x,    // [64][2048][8]
                  const float* __restrict__ W,    // [2048][32][8][16]
                  float* __restrict__ vsum,       // [64][512] f32 o-major
                  __half* __restrict__ part,      // [64][256][512] fp16
                  float* __restrict__ out)        // [64][32][16]
{
    __shared__ __align__(16) float x_lds[32 * 64];   // 8 KB, persists all rounds
    __shared__ __align__(16) char  smem[32768];      // redh | (sA,sB) aliased
    auto redh = reinterpret_cast<__half(*)[16][512]>(smem);          // [2][16][512]
    auto sA   = reinterpret_cast<float(*)[68]>(smem);                // [64][68]
    auto sB   = reinterpret_cast<float(*)[68]>(smem + 64 * 68 * 4);  // [8][68]

    const int t  = threadIdx.x;
    const int w  = t >> 6;
    const int l  = t & 63;
    const int o  = l & 31;
    const int kk = l >> 5;
    const int bx = blockIdx.x;
    const int ch = bx & 255;         // pass: 8-i chunk
    const int h  = bx >> 8;          // pass: b-half
    const int i  = ch * 8 + w;
    const int rb = bx >> 3;          // reduce: b
    const int rq = bx & 7;           // reduce: 64-e slice (4 complete o's)

    // ---- W[i][o][d][kk-half] -> 64 registers, PINNED, loaded ONCE ----------
    float Wr[8][8];
    {
        const float* wp = W + (size_t)(i * 32 + o) * 128 + kk * 8;
        #pragma unroll
        for (int d = 0; d < 8; ++d) {
            float4 a = *(const float4*)(wp + d * 16);
            float4 b = *(const float4*)(wp + d * 16 + 4);
            Wr[d][0] = a.x; Wr[d][1] = a.y; Wr[d][2] = a.z; Wr[d][3] = a.w;
            Wr[d][4] = b.x; Wr[d][5] = b.y; Wr[d][6] = b.z; Wr[d][7] = b.w;
        }
        #pragma unroll
        for (int d = 0; d < 8; ++d)
            #pragma unroll
            for (int j = 0; j < 8; ++j)
                asm volatile("" : "+v"(Wr[d][j]));
    }
    // ---- stage x[h-half, chunk, :] ONCE ------------------------------------
    {
        const int f = t * 4, bl = f >> 6, rr = f & 63;
        *(float4*)&x_lds[f] =
            *(const float4*)(x + (size_t)(h * 32 + bl) * 16384 + ch * 64 + rr);
    }

    cg::grid_group grid = cg::this_grid();

    for (int r = 0; r < 3; ++r) {
        // ====================== pass phase ==================================
        #pragma unroll 2
        for (int g = 0; g < 16; ++g) {       // 2 b's per group
            __syncthreads();                 // redh[g&1] free; g=0: x_lds ready

            if (g && t < 256) {              // fold(g-1) -> part (fp16)
                const int bqf = t >> 7;
                const int hx  = (t & 127) * 4;
                const __half* rp = &redh[(g - 1) & 1][0][0];
                float a0 = 0.f, a1 = 0.f, a2 = 0.f, a3 = 0.f;
                #pragma unroll
                for (int s = 0; s < 8; ++s) {
                    H4 v = *(const H4*)(rp + (s * 2 + bqf) * 512 + hx);
                    float2 f0 = __half22float2(v.a), f1 = __half22float2(v.b);
                    a0 += f0.x; a1 += f0.y; a2 += f1.x; a3 += f1.y;
                }
                const int b = h * 32 + (g - 1) * 2 + bqf;
                H4 o4;
                o4.a = __floats2half2_rn(a0, a1);
                o4.b = __floats2half2_rn(a2, a3);
                *(H4*)(part + ((size_t)b * 256 + ch) * 512 + hx) = o4;
            }

            #pragma unroll
            for (int bq = 0; bq < 2; ++bq) {
                const int bl = g * 2 + bq;
                float4 va, vb;
                if (r) {                     // issue v loads early (L1/L2)
                    const float* vp = vsum + (size_t)(h * 32 + bl) * 512 + o * 16 + kk * 8;
                    va = *(const float4*)vp;
                    vb = *(const float4*)(vp + 4);
                }
                float4 xa = *(const float4*)&x_lds[bl * 64 + w * 8];
                float4 xb = *(const float4*)&x_lds[bl * 64 + w * 8 + 4];
                float xr[8] = {xa.x, xa.y, xa.z, xa.w, xb.x, xb.y, xb.z, xb.w};
                float uh[8];
                #pragma unroll
                for (int j = 0; j < 8; ++j) uh[j] = 0.f;
                #pragma unroll
                for (int d = 0; d < 8; ++d) {
                    #pragma unroll
                    for (int j = 0; j < 8; ++j)
                        uh[j] = fmaf(xr[d], Wr[d][j], uh[j]);
                }
                float c;
                if (r == 0) {
                    c = 0.03125f;            // softmax of zeros
                } else {
                    float logit = uh[0] * va.x;
                    logit = fmaf(uh[1], va.y, logit);
                    logit = fmaf(uh[2], va.z, logit);
                    logit = fmaf(uh[3], va.w, logit);
                    logit = fmaf(uh[4], vb.x, logit);
                    logit = fmaf(uh[5], vb.y, logit);
                    logit = fmaf(uh[6], vb.z, logit);
                    logit = fmaf(uh[7], vb.w, logit);
                    logit += __shfl_xor(logit, 32, 64);   // combine k-halves
                    float ex = __expf(logit);             // |logit| small: no max
                    float sm = ex;                        // o-sum: 4 DPP + xor16
                    sm = dppadd<0xB1>(sm);                // quad_perm xor1
                    sm = dppadd<0x4E>(sm);                // quad_perm xor2
                    sm = dppadd<0x124>(sm);               // row_ror:4
                    sm = dppadd<0x128>(sm);               // row_ror:8
                    sm += __int_as_float(__builtin_amdgcn_ds_swizzle(
                              __float_as_int(sm), 0x401F));   // xor16
                    c = __fdividef(ex, sm);
                }
                H8 pk;
                pk.a = __floats2half2_rn(c * uh[0], c * uh[1]);
                pk.b = __floats2half2_rn(c * uh[2], c * uh[3]);
                pk.c = __floats2half2_rn(c * uh[4], c * uh[5]);
                pk.d = __floats2half2_rn(c * uh[6], c * uh[7]);
                *(H8*)&redh[g & 1][w * 2 + bq][o * 16 + kk * 8] = pk;
            }
        }
        __syncthreads();
        if (t < 256) {                       // epilogue fold(15)
            const int bqf = t >> 7;
            const int hx  = (t & 127) * 4;
            const __half* rp = &redh[1][0][0];
            float a0 = 0.f, a1 = 0.f, a2 = 0.f, a3 = 0.f;
            #pragma unroll
            for (int s = 0; s < 8; ++s) {
                H4 v = *(const H4*)(rp + (s * 2 + bqf) * 512 + hx);
                float2 f0 = __half22float2(v.a), f1 = __half22float2(v.b);
                a0 += f0.x; a1 += f0.y; a2 += f1.x; a3 += f1.y;
            }
            const int b = h * 32 + 30 + bqf;
            H4 o4;
            o4.a = __floats2half2_rn(a0, a1);
            o4.b = __floats2half2_rn(a2, a3);
            *(H4*)(part + ((size_t)b * 256 + ch) * 512 + hx) = o4;
        }
        __threadfence();
        grid.sync();                         // part complete, grid-visible

        // ====================== reduce phase ================================
        {
            const int f  = t & 7;            // 16B segment in the 64-e slice
            const int c0 = t >> 3;           // chunk row base in [0,64)
            const __half* p0 = part + ((size_t)rb * 256 + c0) * 512 + rq * 64 + f * 8;
            float acc[8] = {0.f, 0.f, 0.f, 0.f, 0.f, 0.f, 0.f, 0.f};
            #pragma unroll
            for (int k = 0; k < 4; ++k) {    // rows c0, c0+64, c0+128, c0+192
                H8 v = *(const H8*)(p0 + (size_t)k * 64 * 512);
                float2 f0 = __half22float2(v.a), f1 = __half22float2(v.b),
                       f2 = __half22float2(v.c), f3 = __half22float2(v.d);
                acc[0] += f0.x; acc[1] += f0.y; acc[2] += f1.x; acc[3] += f1.y;
                acc[4] += f2.x; acc[5] += f2.y; acc[6] += f3.x; acc[7] += f3.y;
            }
            *(float4*)&sA[c0][f * 8]     = make_float4(acc[0], acc[1], acc[2], acc[3]);
            *(float4*)&sA[c0][f * 8 + 4] = make_float4(acc[4], acc[5], acc[6], acc[7]);
        }
        __syncthreads();
        {                                    // 64 rows -> 8
            const int e = t & 63, rr = t >> 6;
            float sb = 0.f;
            #pragma unroll
            for (int k = 0; k < 8; ++k) sb += sA[rr + k * 8][e];
            sB[rr][e] = sb;
        }
        __syncthreads();
        if (t < 64) {                        // one wave: 8 rows, squash
            float s1 = 0.f;
            #pragma unroll
            for (int rr = 0; rr < 8; ++rr) s1 += sB[rr][t];
            float sq = s1 * s1;
            #pragma unroll
            for (int off = 8; off >= 1; off >>= 1)
                sq += __shfl_xor(sq, off, 16);     // sum over 16 k within o
            float v = (sq / (1.f + sq) * rsqrtf(sq + 1e-7f)) * s1;
            const size_t idx = (size_t)rb * 512 + rq * 64 + t;
            if (r == 2)      out[idx]   = v;       // e = o*16+k == [b][o][k]
            else if (r == 1) vsum[idx] += v;
            else             vsum[idx]  = v;
        }
        if (r < 2) { __threadfence(); grid.sync(); }   // vsum visible, part free
    }
}

// ===========================================================================
// Fallback path (round-4 proven kernels) if cooperative launch is rejected.
// ===========================================================================
template<int PASS0>
__global__ __launch_bounds__(512, 4)
void pass_kernel(const float* __restrict__ x, const float* __restrict__ W,
                 const float* __restrict__ vin, __half* __restrict__ part)
{
    __shared__ __align__(16) float  x_lds[32 * 64];
    __shared__ __align__(16) __half redh[2][16][512];

    const int t = threadIdx.x, w = t >> 6, l = t & 63, o = l & 31, kk = l >> 5;
    const int bx = blockIdx.x, ch = bx & 255, h = bx >> 8, i = ch * 8 + w;

    float Wr[8][8];
    {
        const float* wp = W + (size_t)(i * 32 + o) * 128 + kk * 8;
        #pragma unroll
        for (int d = 0; d < 8; ++d) {
            float4 a = *(const float4*)(wp + d * 16);
            float4 b = *(const float4*)(wp + d * 16 + 4);
            Wr[d][0] = a.x; Wr[d][1] = a.y; Wr[d][2] = a.z; Wr[d][3] = a.w;
            Wr[d][4] = b.x; Wr[d][5] = b.y; Wr[d][6] = b.z; Wr[d][7] = b.w;
        }
        #pragma unroll
        for (int d = 0; d < 8; ++d)
            #pragma unroll
            for (int j = 0; j < 8; ++j)
                asm volatile("" : "+v"(Wr[d][j]));
    }
    {
        const int f = t * 4, bl = f >> 6, rr = f & 63;
        *(float4*)&x_lds[f] =
            *(const float4*)(x + (size_t)(h * 32 + bl) * 16384 + ch * 64 + rr);
    }

    #pragma unroll 2
    for (int g = 0; g < 16; ++g) {
        __syncthreads();
        if (g && t < 256) {
            const int bqf = t >> 7, hx = (t & 127) * 4;
            const __half* rp = &redh[(g - 1) & 1][0][0];
            float a0 = 0.f, a1 = 0.f, a2 = 0.f, a3 = 0.f;
            #pragma unroll
            for (int s = 0; s < 8; ++s) {
                H4 v = *(const H4*)(rp + (s * 2 + bqf) * 512 + hx);
                float2 f0 = __half22float2(v.a), f1 = __half22float2(v.b);
                a0 += f0.x; a1 += f0.y; a2 += f1.x; a3 += f1.y;
            }
            const int b = h * 32 + (g - 1) * 2 + bqf;
            H4 o4; o4.a = __floats2half2_rn(a0, a1); o4.b = __floats2half2_rn(a2, a3);
            *(H4*)(part + ((size_t)b * 256 + ch) * 512 + hx) = o4;
        }
        #pragma unroll
        for (int bq = 0; bq < 2; ++bq) {
            const int bl = g * 2 + bq;
            float4 va, vb;
            if (!PASS0) {
                const float* vp = vin + (size_t)(h * 32 + bl) * 512 + o * 16 + kk * 8;
                va = *(const float4*)vp; vb = *(const float4*)(vp + 4);
            }
            float4 xa = *(const float4*)&x_lds[bl * 64 + w * 8];
            float4 xb = *(const float4*)&x_lds[bl * 64 + w * 8 + 4];
            float xr[8] = {xa.x, xa.y, xa.z, xa.w, xb.x, xb.y, xb.z, xb.w};
            float uh[8];
            #pragma unroll
            for (int j = 0; j < 8; ++j) uh[j] = 0.f;
            #pragma unroll
            for (int d = 0; d < 8; ++d)
                #pragma unroll
                for (int j = 0; j < 8; ++j)
                    uh[j] = fmaf(xr[d], Wr[d][j], uh[j]);
            float c;
            if (PASS0) {
                c = 0.03125f;
            } else {
                float logit = uh[0] * va.x;
                logit = fmaf(uh[1], va.y, logit);
                logit = fmaf(uh[2], va.z, logit);
                logit = fmaf(uh[3], va.w, logit);
                logit = fmaf(uh[4], vb.x, logit);
                logit = fmaf(uh[5], vb.y, logit);
                logit = fmaf(uh[6], vb.z, logit);
                logit = fmaf(uh[7], vb.w, logit);
                logit += __shfl_xor(logit, 32, 64);
                float ex = __expf(logit);
                float sm = ex;
                sm = dppadd<0xB1>(sm);
                sm = dppadd<0x4E>(sm);
                sm = dppadd<0x124>(sm);
                sm = dppadd<0x128>(sm);
                sm += __int_as_float(__builtin_amdgcn_ds_swizzle(
                          __float_as_int(sm), 0x401F));
                c = __fdividef(ex, sm);
            }
            H8 pk;
            pk.a = __floats2half2_rn(c * uh[0], c * uh[1]);
            pk.b = __floats2half2_rn(c * uh[2], c * uh[3]);
            pk.c = __floats2half2_rn(c * uh[4], c * uh[5]);
            pk.d = __floats2half2_rn(c * uh[6], c * uh[7]);
            *(H8*)&redh[g & 1][w * 2 + bq][o * 16 + kk * 8] = pk;
        }
    }
    __syncthreads();
    if (t < 256) {
        const int bqf = t >> 7, hx = (t & 127) * 4;
        const __half* rp = &redh[1][0][0];
        float a0 = 0.f, a1 = 0.f, a2 = 0.f, a3 = 0.f;
        #pragma unroll
        for (int s = 0; s < 8; ++s) {
            H4 v = *(const H4*)(rp + (s * 2 + bqf) * 512 + hx);
            float2 f0 = __half22float2(v.a), f1 = __half22float2(v.b);
            a0 += f0.x; a1 += f0.y; a2 += f1.x; a3 += f1.y;
        }
        const int b = h * 32 + 30 + bqf;
        H4 o4; o4.a = __floats2half2_rn(a0, a1); o4.b = __floats2half2_rn(a2, a3);
        *(H4*)(part + ((size_t)b * 256 + ch) * 512 + hx) = o4;
    }
}

template<int PHASE>
__global__ __launch_bounds__(1024)
void reduce_kernel(const __half* __restrict__ part,
                   float* __restrict__ vsum, float* __restrict__ out)
{
    __shared__ __align__(16) float sA[128][64];
    __shared__ __align__(16) float sB[16][64];
    const int bx = blockIdx.x, b = bx >> 3, q = bx & 7;
    const int t = threadIdx.x, f = t & 7, c0 = t >> 3;

    const __half* p0 = part + ((size_t)b * 256 + c0) * 512 + q * 64 + f * 8;
    float acc[8] = {0.f, 0.f, 0.f, 0.f, 0.f, 0.f, 0.f, 0.f};
    #pragma unroll
    for (int rr = 0; rr < 2; ++rr) {
        H8 v = *(const H8*)(p0 + (size_t)rr * 128 * 512);
        float2 f0 = __half22float2(v.a), f1 = __half22float2(v.b),
               f2 = __half22float2(v.c), f3 = __half22float2(v.d);
        acc[0] += f0.x; acc[1] += f0.y; acc[2] += f1.x; acc[3] += f1.y;
        acc[4] += f2.x; acc[5] += f2.y; acc[6] += f3.x; acc[7] += f3.y;
    }
    *(float4*)&sA[c0][f * 8]     = make_float4(acc[0], acc[1], acc[2], acc[3]);
    *(float4*)&sA[c0][f * 8 + 4] = make_float4(acc[4], acc[5], acc[6], acc[7]);
    __syncthreads();
    {
        const int e = t & 63, r4 = t >> 6;
        float sb = 0.f;
        #pragma unroll
        for (int k2 = 0; k2 < 8; ++k2) sb += sA[r4 + k2 * 16][e];
        sB[r4][e] = sb;
    }
    __syncthreads();
    if (t < 64) {
        float s1 = 0.f;
        #pragma unroll
        for (int rr = 0; rr < 16; ++rr) s1 += sB[rr][t];
        float sq = s1 * s1;
        #pragma unroll
        for (int off = 8; off >= 1; off >>= 1)
            sq += __shfl_xor(sq, off, 16);
        float v = (sq / (1.f + sq) * rsqrtf(sq + 1e-7f)) * s1;
        const size_t idx = (size_t)b * 512 + q * 64 + t;
        if (PHASE == 2)      out[idx]   = v;
        else if (PHASE == 1) vsum[idx] += v;
        else                 vsum[idx]  = v;
    }
}

// ---------------------------------------------------------------------------
extern "C" void kernel_launch(void* const* d_in, const int* in_sizes, int n_in,
                              void* d_out, int out_size, void* d_ws, size_t ws_size,
                              hipStream_t stream)
{
    const float* x = (const float*)d_in[0];
    const float* W = (const float*)d_in[1];
    float* out = (float*)d_out;
    char* ws = (char*)d_ws;

    const size_t partB = (size_t)64 * 256 * 512 * 2;   // 16 MB (fp16)
    const size_t vsumB = (size_t)64 * 512 * 4;         // 128 KB
    if (ws_size < partB + vsumB) return;               // never taken

    __half* part = (__half*)ws;
    float*  vsum = (float*)(ws + partB);

    void* args[] = {(void*)&x, (void*)&W, (void*)&vsum, (void*)&part, (void*)&out};
    hipError_t err = hipLaunchCooperativeKernel(
        (const void*)fused_kernel, dim3(512), dim3(512), args, 0, stream);
    if (err == hipSuccess) return;

    // fallback: proven 6-launch path
    pass_kernel<1><<<512, 512, 0, stream>>>(x, W, vsum, part);
    reduce_kernel<0><<<512, 1024, 0, stream>>>(part, vsum, out);
    pass_kernel<0><<<512, 512, 0, stream>>>(x, W, vsum, part);
    reduce_kernel<1><<<512, 1024, 0, stream>>>(part, vsum, out);
    pass_kernel<0><<<512, 512, 0, stream>>>(x, W, vsum, part);
    reduce_kernel<2><<<512, 1024, 0, stream>>>(part, vsum, out);
}